// Round 4
// baseline (196.496 us; speedup 1.0000x reference)
//
#include <hip/hip_runtime.h>

#define BB 8
#define LL 2048
#define DD 512
#define NN 64
#define TT 64
#define CC 32   // LL/TT chunks

__device__ __forceinline__ float2 cmul(float2 a, float2 b) {
  return make_float2(a.x*b.x - a.y*b.y, a.x*b.y + a.y*b.x);
}

// ---------------------------------------------------------------------------
// K1: per-d setup. 64 threads = one wave, lane = n.
// Emits: W[d][s][n] = Abar^(63-s)*Bbar   (phase-B weights, coalesced in n)
//        G[d][n][r] = C*Abar^(r+1)       (phase-D weights, coalesced in r)
//        P[d][n]    = Abar^64            (scan propagator)
//        KlocT[m][d]= Re(sum_n C*Abar^m*Bbar)  (conv taps, coalesced in d)
// ---------------------------------------------------------------------------
__global__ __launch_bounds__(64) void k1_setup(
    const float* __restrict__ A_re, const float* __restrict__ A_im,
    const float* __restrict__ C_re, const float* __restrict__ C_im,
    const float* __restrict__ log_dt,
    float2* __restrict__ W, float2* __restrict__ G,
    float2* __restrict__ P, float* __restrict__ KlocT) {
  int d = blockIdx.x, n = threadIdx.x;
  int idx = d * NN + n;
  float dt  = expf(log_dt[d]);
  float dre = dt * A_re[idx], dim = dt * A_im[idx];
  float er  = expf(dre);
  float abr = er * cosf(dim), abi = er * sinf(dim);
  const float eps = 1e-8f;
  float nre = abr - 1.0f + eps, nim = abi;
  float qre = dre + eps,        qim = dim;
  float inv = 1.0f / (qre*qre + qim*qim);
  float bbr = dt * (nre*qre + nim*qim) * inv;
  float bbi = dt * (nim*qre - nre*qim) * inv;
  float2 a  = make_float2(abr, abi);
  float2 bb = make_float2(bbr, bbi);
  float2 cc = make_float2(C_re[idx], C_im[idx]);

  // W chain: W[s=63]=Bbar, W[s-1]=W[s]*a
  {
    float2 w = bb;
    for (int s = TT - 1; s >= 0; --s) {
      W[((size_t)d * TT + s) * NN + n] = w;
      w = cmul(w, a);
    }
  }
  // G chain: G[r]=C*a^(r+1)
  {
    float2 g = cmul(cc, a);
    for (int r = 0; r < TT; ++r) {
      G[((size_t)d * NN + n) * TT + r] = g;
      g = cmul(g, a);
    }
  }
  // P = a^64
  {
    float2 p = a;
    #pragma unroll
    for (int q = 0; q < 6; ++q) p = cmul(p, p);
    P[idx] = p;
  }
  // K_loc[m] = Re(sum_n C*Abar^m*Bbar)
  float tre = cc.x*bb.x - cc.y*bb.y;
  float tim = cc.x*bb.y + cc.y*bb.x;
  for (int m = 0; m < TT; ++m) {
    float v = tre;
    #pragma unroll
    for (int off = 32; off > 0; off >>= 1) v += __shfl_down(v, off, 64);
    if (n == 0) KlocT[m * DD + d] = v;
    float t2 = tre*abr - tim*abi;
    tim = tre*abi + tim*abr;
    tre = t2;
  }
}

// ---------------------------------------------------------------------------
// K2 fused: Z + in-block chunk scan + cross-term. One block per (b,d).
// W and G streamed from global (coalesced, L2/L3); LDS = 16 KB only
// (Zs, with the u column aliased inside it during phases A-B).
//   A: gather-stage u column
//   B: Z_c[n] = sum_s W[s][n]*u[cT+s]; wave wv owns chunks wv*8..wv*8+7
//   C: 32-step scan (wave 0): Zs[c] <- S_c (state BEFORE chunk c)
//   D: ycross[c][r] = Re(sum_n G[n][r]*S_c[n]); lane = r
// ---------------------------------------------------------------------------
__global__ __launch_bounds__(256, 5) void k2_fused(
    const float* __restrict__ u, const float2* __restrict__ W,
    const float2* __restrict__ G, const float2* __restrict__ P,
    float* __restrict__ ycross) {
  int bid = blockIdx.x;
  int b = bid & 7, d = bid >> 3;       // b = XCD: u[b] slice stays L2-local
  int tid = threadIdx.x;
  int n = tid & 63;
  int wv = tid >> 6;
  int c0 = wv * 8;

  __shared__ __align__(16) float2 Zs[CC * NN];   // 16 KB
  float* ul = (float*)Zs;                        // 8 KB alias, dies end of B

  // --- A: stage u column (strided gather, L2-resident per XCD)
  for (int i = tid; i < LL; i += 256)
    ul[i] = u[((size_t)b * LL + i) * DD + d];
  __syncthreads();

  // --- B: Z for my 8 chunks; W streamed (coalesced b64 per lane)
  float2 acc[8];
  #pragma unroll
  for (int i = 0; i < 8; ++i) acc[i] = make_float2(0.f, 0.f);
  {
    const float2* Wp = W + (size_t)d * TT * NN + n;
    #pragma unroll 2
    for (int s0 = 0; s0 < TT; s0 += 4) {
      float2 w0 = Wp[(s0 + 0) * NN];
      float2 w1 = Wp[(s0 + 1) * NN];
      float2 w2 = Wp[(s0 + 2) * NN];
      float2 w3 = Wp[(s0 + 3) * NN];
      #pragma unroll
      for (int i = 0; i < 8; ++i) {
        float4 uv = *(const float4*)&ul[(c0 + i) * TT + s0];  // broadcast b128
        acc[i].x = fmaf(w0.x, uv.x, fmaf(w1.x, uv.y,
                   fmaf(w2.x, uv.z, fmaf(w3.x, uv.w, acc[i].x))));
        acc[i].y = fmaf(w0.y, uv.x, fmaf(w1.y, uv.y,
                   fmaf(w2.y, uv.z, fmaf(w3.y, uv.w, acc[i].y))));
      }
    }
  }
  __syncthreads();                     // all ul reads done (Zs overwrites it)
  #pragma unroll
  for (int i = 0; i < 8; ++i) Zs[(c0 + i) * NN + n] = acc[i];
  __syncthreads();

  // --- C: scan (wave 0): Zs[c] := S_c; S_{c+1} = a^64*S_c + Z_c
  if (wv == 0) {
    float2 p = P[(size_t)d * NN + n];
    float2 s = make_float2(0.f, 0.f);
    for (int c = 0; c < CC; ++c) {
      float2 z = Zs[c * NN + n];
      Zs[c * NN + n] = s;
      float2 ps = cmul(p, s);
      s = make_float2(ps.x + z.x, ps.y + z.y);
    }
  }
  __syncthreads();

  // --- D: ycross[c][r] = Re(sum_n G[n][r]*S_c[n]); lane = r = n
  {
    const float2* Gp = G + (size_t)d * NN * TT + n;   // lane stride 8B
    float acc2[8];
    #pragma unroll
    for (int i = 0; i < 8; ++i) acc2[i] = 0.f;
    #pragma unroll 4
    for (int nn = 0; nn < NN; nn += 2) {
      float2 g0 = Gp[(nn + 0) * TT];
      float2 g1 = Gp[(nn + 1) * TT];
      #pragma unroll
      for (int i = 0; i < 8; ++i) {
        float4 s01 = *(const float4*)&Zs[(c0 + i) * NN + nn];  // broadcast b128
        acc2[i] = fmaf(g0.x, s01.x, fmaf(-g0.y, s01.y,
                  fmaf(g1.x, s01.z, fmaf(-g1.y, s01.w, acc2[i]))));
      }
    }
    float* yp = ycross + ((size_t)d * 256 + b * CC) * TT;
    #pragma unroll
    for (int i = 0; i < 8; ++i)
      yp[(size_t)(c0 + i) * TT + n] = acc2[i];        // coalesced 256B/wave
  }
}

// ---------------------------------------------------------------------------
// K3b: local causal 64-tap conv + cross term, coalesced y writes.
// Sliding 8-r register window over zero-padded u rows.
// ---------------------------------------------------------------------------
__global__ __launch_bounds__(256, 2) void k3b_out(
    const float* __restrict__ u, const float* __restrict__ KlocT,
    const float* __restrict__ ycross, float* __restrict__ y) {
  int bid = blockIdx.x;
  int d8 = bid & 7;
  int c  = (bid >> 3) & (CC - 1);
  int b  = bid >> 8;
  int d0 = d8 * 64;
  int tid = threadIdx.x;
  int dd = tid & 63, rq = tid >> 6;
  __shared__ float ulp[128][64];       // ulp[63+t][dd]=u[cT+t], rows<63 = 0
  __shared__ float Ktl[TT][64];
  __shared__ float ycl[64][65];
  for (int i = tid; i < 63 * 64; i += 256)
    ulp[i >> 6][i & 63] = 0.f;
  for (int i = tid; i < TT * 64; i += 256) {
    int s = i >> 6, e = i & 63;
    ulp[63 + s][e] = u[((size_t)b * LL + c * TT + s) * DD + d0 + e];
    Ktl[s][e] = KlocT[s * DD + d0 + e];
  }
  for (int i = tid; i < 64 * TT; i += 256) {
    int e = i >> 6, r = i & 63;
    ycl[e][r] = ycross[((size_t)(d0 + e) * 256 + b * CC + c) * TT + r];
  }
  __syncthreads();
  #pragma unroll 1
  for (int pass = 0; pass < 2; ++pass) {
    int rg = rq + 4 * pass;            // wave-uniform
    int r0 = rg * 8;
    float acc[8], w[8];
    #pragma unroll
    for (int j = 0; j < 8; ++j) acc[j] = ycl[dd][r0 + j];
    #pragma unroll
    for (int j = 0; j < 8; ++j) w[j] = ulp[63 + r0 + j][dd];
    for (int m0 = 0; m0 <= r0; m0 += 8) {
      #pragma unroll
      for (int mm = 0; mm < 8; ++mm) {
        float kv = Ktl[m0 + mm][dd];
        #pragma unroll
        for (int j = 0; j < 8; ++j)
          acc[j] = fmaf(kv, w[(j - mm) & 7], acc[j]);
        w[(7 - mm) & 7] = ulp[63 + r0 - 1 - (m0 + mm)][dd];
      }
    }
    #pragma unroll
    for (int j = 0; j < 8; ++j)
      y[((size_t)b * LL + c * TT + r0 + j) * DD + d0 + dd] = acc[j];
  }
}

extern "C" void kernel_launch(void* const* d_in, const int* in_sizes, int n_in,
                              void* d_out, int out_size, void* d_ws, size_t ws_size,
                              hipStream_t stream) {
  const float* u      = (const float*)d_in[0];
  const float* A_re   = (const float*)d_in[1];
  const float* A_im   = (const float*)d_in[2];
  const float* C_re   = (const float*)d_in[3];
  const float* C_im   = (const float*)d_in[4];
  const float* log_dt = (const float*)d_in[5];
  float* y  = (float*)d_out;
  float* ws = (float*)d_ws;

  // ws layout (floats): ycross 33.6MB | W 16.8MB | G 16.8MB | P | KlocT
  float*  ycross = ws;
  float2* W      = (float2*)(ycross + (size_t)DD * BB * CC * TT);
  float2* G      = W + (size_t)DD * TT * NN;
  float2* P      = G + (size_t)DD * NN * TT;
  float*  KlocT  = (float*)(P + DD * NN);

  k1_setup<<<DD,                64,  0, stream>>>(A_re, A_im, C_re, C_im, log_dt,
                                                  W, G, P, KlocT);
  k2_fused<<<BB * DD,           256, 0, stream>>>(u, W, G, P, ycross);
  k3b_out <<<BB * CC * (DD/64), 256, 0, stream>>>(u, KlocT, ycross, y);
}

// Round 5
// 161.826 us; speedup vs baseline: 1.2142x; 1.2142x over previous
//
#include <hip/hip_runtime.h>

#define BB 8
#define LL 2048
#define DD 512
#define NN 64
#define TT 64
#define CC 32   // LL/TT chunks

__device__ __forceinline__ float2 cmul(float2 a, float2 b) {
  return make_float2(a.x*b.x - a.y*b.y, a.x*b.y + a.y*b.x);
}

// ---------------------------------------------------------------------------
// K1: per-d setup. 64 threads = one wave, lane = n.
// Emits: W[d][s][n] = Abar^(63-s)*Bbar   (phase-B weights, coalesced in n)
//        G[d][n][r] = C*Abar^(r+1)       (phase-D weights, coalesced in r)
//        P[d][n]    = Abar^64            (scan propagator)
//        KlocT[m][d]= Re(sum_n C*Abar^m*Bbar)  (conv taps, coalesced in d)
// ---------------------------------------------------------------------------
__global__ __launch_bounds__(64) void k1_setup(
    const float* __restrict__ A_re, const float* __restrict__ A_im,
    const float* __restrict__ C_re, const float* __restrict__ C_im,
    const float* __restrict__ log_dt,
    float2* __restrict__ W, float2* __restrict__ G,
    float2* __restrict__ P, float* __restrict__ KlocT) {
  int d = blockIdx.x, n = threadIdx.x;
  int idx = d * NN + n;
  float dt  = expf(log_dt[d]);
  float dre = dt * A_re[idx], dim = dt * A_im[idx];
  float er  = expf(dre);
  float abr = er * cosf(dim), abi = er * sinf(dim);
  const float eps = 1e-8f;
  float nre = abr - 1.0f + eps, nim = abi;
  float qre = dre + eps,        qim = dim;
  float inv = 1.0f / (qre*qre + qim*qim);
  float bbr = dt * (nre*qre + nim*qim) * inv;
  float bbi = dt * (nim*qre - nre*qim) * inv;
  float2 a  = make_float2(abr, abi);
  float2 bb = make_float2(bbr, bbi);
  float2 cc = make_float2(C_re[idx], C_im[idx]);

  // W chain: W[s=63]=Bbar, W[s-1]=W[s]*a
  {
    float2 w = bb;
    for (int s = TT - 1; s >= 0; --s) {
      W[((size_t)d * TT + s) * NN + n] = w;
      w = cmul(w, a);
    }
  }
  // G chain: G[r]=C*a^(r+1)
  {
    float2 g = cmul(cc, a);
    for (int r = 0; r < TT; ++r) {
      G[((size_t)d * NN + n) * TT + r] = g;
      g = cmul(g, a);
    }
  }
  // P = a^64
  {
    float2 p = a;
    #pragma unroll
    for (int q = 0; q < 6; ++q) p = cmul(p, p);
    P[idx] = p;
  }
  // K_loc[m] = Re(sum_n C*Abar^m*Bbar)
  float tre = cc.x*bb.x - cc.y*bb.y;
  float tim = cc.x*bb.y + cc.y*bb.x;
  for (int m = 0; m < TT; ++m) {
    float v = tre;
    #pragma unroll
    for (int off = 32; off > 0; off >>= 1) v += __shfl_down(v, off, 64);
    if (n == 0) KlocT[m * DD + d] = v;
    float t2 = tre*abr - tim*abi;
    tim = tre*abi + tim*abr;
    tre = t2;
  }
}

// ---------------------------------------------------------------------------
// K2 fused: Z + in-block chunk scan + cross-term. One block per (b,d).
// XCD swizzle: XCD x = bid&7 hosts d in [x*64, x*64+64) -> per-XCD weight
// working set = 64 d * 64KB = 4MB = L2 size, so W/G stream at L2 speed and
// are fetched from HBM ~once; u lines (16 consecutive d) are consumed
// entirely within one XCD by co-resident same-b blocks.
//   A: gather-stage u column
//   B: Z_c[n] = sum_s W[s][n]*u[cT+s]; wave wv owns chunks wv*8..wv*8+7
//   C: 32-step scan (wave 0): Zs[c] <- S_c (state BEFORE chunk c)
//   D: ycross[c][r] = Re(sum_n G[n][r]*S_c[n]); lane = r
// LDS 16 KB only -> 8 blocks/CU.
// ---------------------------------------------------------------------------
__global__ __launch_bounds__(256, 8) void k2_fused(
    const float* __restrict__ u, const float2* __restrict__ W,
    const float2* __restrict__ G, const float2* __restrict__ P,
    float* __restrict__ ycross) {
  int bid = blockIdx.x;
  int x = bid & 7;                     // XCD
  int d = x * 64 + ((bid >> 3) & 63);  // d-contiguous per XCD
  int b = bid >> 9;
  int tid = threadIdx.x;
  int n = tid & 63;
  int wv = tid >> 6;
  int c0 = wv * 8;

  __shared__ __align__(16) float2 Zs[CC * NN];   // 16 KB
  float* ul = (float*)Zs;                        // 8 KB alias, dies end of B

  // --- A: stage u column (strided gather; lines L2-shared with d-neighbors)
  for (int i = tid; i < LL; i += 256)
    ul[i] = u[((size_t)b * LL + i) * DD + d];
  __syncthreads();

  // --- B: Z for my 8 chunks; W streamed (coalesced b64, L2-hot)
  float2 acc[8];
  #pragma unroll
  for (int i = 0; i < 8; ++i) acc[i] = make_float2(0.f, 0.f);
  {
    const float2* Wp = W + (size_t)d * TT * NN + n;
    #pragma unroll 2
    for (int s0 = 0; s0 < TT; s0 += 4) {
      float2 w0 = Wp[(s0 + 0) * NN];
      float2 w1 = Wp[(s0 + 1) * NN];
      float2 w2 = Wp[(s0 + 2) * NN];
      float2 w3 = Wp[(s0 + 3) * NN];
      #pragma unroll
      for (int i = 0; i < 8; ++i) {
        float4 uv = *(const float4*)&ul[(c0 + i) * TT + s0];  // broadcast b128
        acc[i].x = fmaf(w0.x, uv.x, fmaf(w1.x, uv.y,
                   fmaf(w2.x, uv.z, fmaf(w3.x, uv.w, acc[i].x))));
        acc[i].y = fmaf(w0.y, uv.x, fmaf(w1.y, uv.y,
                   fmaf(w2.y, uv.z, fmaf(w3.y, uv.w, acc[i].y))));
      }
    }
  }
  __syncthreads();                     // all ul reads done (Zs overwrites it)
  #pragma unroll
  for (int i = 0; i < 8; ++i) Zs[(c0 + i) * NN + n] = acc[i];
  __syncthreads();

  // --- C: scan (wave 0): Zs[c] := S_c; S_{c+1} = a^64*S_c + Z_c
  if (wv == 0) {
    float2 p = P[(size_t)d * NN + n];
    float2 s = make_float2(0.f, 0.f);
    for (int c = 0; c < CC; ++c) {
      float2 z = Zs[c * NN + n];
      Zs[c * NN + n] = s;
      float2 ps = cmul(p, s);
      s = make_float2(ps.x + z.x, ps.y + z.y);
    }
  }
  __syncthreads();

  // --- D: ycross[c][r] = Re(sum_n G[n][r]*S_c[n]); lane = r = n
  {
    const float2* Gp = G + (size_t)d * NN * TT + n;   // coalesced, L2-hot
    float acc2[8];
    #pragma unroll
    for (int i = 0; i < 8; ++i) acc2[i] = 0.f;
    #pragma unroll 4
    for (int nn = 0; nn < NN; nn += 2) {
      float2 g0 = Gp[(nn + 0) * TT];
      float2 g1 = Gp[(nn + 1) * TT];
      #pragma unroll
      for (int i = 0; i < 8; ++i) {
        float4 s01 = *(const float4*)&Zs[(c0 + i) * NN + nn];  // broadcast b128
        acc2[i] = fmaf(g0.x, s01.x, fmaf(-g0.y, s01.y,
                  fmaf(g1.x, s01.z, fmaf(-g1.y, s01.w, acc2[i]))));
      }
    }
    float* yp = ycross + ((size_t)d * 256 + b * CC) * TT;
    #pragma unroll
    for (int i = 0; i < 8; ++i)
      yp[(size_t)(c0 + i) * TT + n] = acc2[i];        // coalesced 256B/wave
  }
}

// ---------------------------------------------------------------------------
// K3b: local causal 64-tap conv + cross term, coalesced y writes.
// Sliding 8-r register window over zero-padded u rows.
// ---------------------------------------------------------------------------
__global__ __launch_bounds__(256, 2) void k3b_out(
    const float* __restrict__ u, const float* __restrict__ KlocT,
    const float* __restrict__ ycross, float* __restrict__ y) {
  int bid = blockIdx.x;
  int d8 = bid & 7;
  int c  = (bid >> 3) & (CC - 1);
  int b  = bid >> 8;
  int d0 = d8 * 64;
  int tid = threadIdx.x;
  int dd = tid & 63, rq = tid >> 6;
  __shared__ float ulp[128][64];       // ulp[63+t][dd]=u[cT+t], rows<63 = 0
  __shared__ float Ktl[TT][64];
  __shared__ float ycl[64][65];
  for (int i = tid; i < 63 * 64; i += 256)
    ulp[i >> 6][i & 63] = 0.f;
  for (int i = tid; i < TT * 64; i += 256) {
    int s = i >> 6, e = i & 63;
    ulp[63 + s][e] = u[((size_t)b * LL + c * TT + s) * DD + d0 + e];
    Ktl[s][e] = KlocT[s * DD + d0 + e];
  }
  for (int i = tid; i < 64 * TT; i += 256) {
    int e = i >> 6, r = i & 63;
    ycl[e][r] = ycross[((size_t)(d0 + e) * 256 + b * CC + c) * TT + r];
  }
  __syncthreads();
  #pragma unroll 1
  for (int pass = 0; pass < 2; ++pass) {
    int rg = rq + 4 * pass;            // wave-uniform
    int r0 = rg * 8;
    float acc[8], w[8];
    #pragma unroll
    for (int j = 0; j < 8; ++j) acc[j] = ycl[dd][r0 + j];
    #pragma unroll
    for (int j = 0; j < 8; ++j) w[j] = ulp[63 + r0 + j][dd];
    for (int m0 = 0; m0 <= r0; m0 += 8) {
      #pragma unroll
      for (int mm = 0; mm < 8; ++mm) {
        float kv = Ktl[m0 + mm][dd];
        #pragma unroll
        for (int j = 0; j < 8; ++j)
          acc[j] = fmaf(kv, w[(j - mm) & 7], acc[j]);
        w[(7 - mm) & 7] = ulp[63 + r0 - 1 - (m0 + mm)][dd];
      }
    }
    #pragma unroll
    for (int j = 0; j < 8; ++j)
      y[((size_t)b * LL + c * TT + r0 + j) * DD + d0 + dd] = acc[j];
  }
}

extern "C" void kernel_launch(void* const* d_in, const int* in_sizes, int n_in,
                              void* d_out, int out_size, void* d_ws, size_t ws_size,
                              hipStream_t stream) {
  const float* u      = (const float*)d_in[0];
  const float* A_re   = (const float*)d_in[1];
  const float* A_im   = (const float*)d_in[2];
  const float* C_re   = (const float*)d_in[3];
  const float* C_im   = (const float*)d_in[4];
  const float* log_dt = (const float*)d_in[5];
  float* y  = (float*)d_out;
  float* ws = (float*)d_ws;

  // ws layout (floats): ycross 33.6MB | W 16.8MB | G 16.8MB | P | KlocT
  float*  ycross = ws;
  float2* W      = (float2*)(ycross + (size_t)DD * BB * CC * TT);
  float2* G      = W + (size_t)DD * TT * NN;
  float2* P      = G + (size_t)DD * NN * TT;
  float*  KlocT  = (float*)(P + DD * NN);

  k1_setup<<<DD,                64,  0, stream>>>(A_re, A_im, C_re, C_im, log_dt,
                                                  W, G, P, KlocT);
  k2_fused<<<BB * DD,           256, 0, stream>>>(u, W, G, P, ycross);
  k3b_out <<<BB * CC * (DD/64), 256, 0, stream>>>(u, KlocT, ycross, y);
}

// Round 6
// 113.753 us; speedup vs baseline: 1.7274x; 1.4226x over previous
//
#include <hip/hip_runtime.h>

#define BB 8
#define LL 2048
#define DD 512
#define NN 64
#define TT 64
#define CC 32   // LL/TT chunks

typedef __attribute__((ext_vector_type(8))) short bf16x8;
typedef __attribute__((ext_vector_type(4))) float f32x4;

__device__ __forceinline__ float2 cmul(float2 a, float2 b) {
  return make_float2(a.x*b.x - a.y*b.y, a.x*b.y + a.y*b.x);
}
__device__ __forceinline__ unsigned f2b(float f) {   // f32 -> bf16 (RNE)
  union { float f; unsigned u; } v; v.f = f;
  return (v.u + 0x7FFFu + ((v.u >> 16) & 1u)) >> 16;
}
__device__ __forceinline__ float b2f(unsigned h) {
  union { unsigned u; float f; } v; v.u = h << 16; return v.f;
}

// ---------------------------------------------------------------------------
// K1: per-d setup. 64 threads = one wave, lane = n. Emits bf16 MFMA operands:
//  W2t[d][n2][s]  n2=2n: Re(Abar^(63-s)*Bbar), n2=2n+1: Im  (B-op, phase B)
//  G2t[d][r][n2]  n2=2n: Re(C*Abar^(r+1)),     n2=2n+1: -Im (B-op, phase D)
//  P[d][n] = Abar^64 (f32 scan propagator); KlocT[m][d] (f32 conv taps)
// ---------------------------------------------------------------------------
__global__ __launch_bounds__(64) void k1_setup(
    const float* __restrict__ A_re, const float* __restrict__ A_im,
    const float* __restrict__ C_re, const float* __restrict__ C_im,
    const float* __restrict__ log_dt,
    ushort* __restrict__ W2t, ushort* __restrict__ G2t,
    float2* __restrict__ P, float* __restrict__ KlocT) {
  int d = blockIdx.x, n = threadIdx.x;
  int idx = d * NN + n;
  float dt  = expf(log_dt[d]);
  float dre = dt * A_re[idx], dim = dt * A_im[idx];
  float er  = expf(dre);
  float abr = er * cosf(dim), abi = er * sinf(dim);
  const float eps = 1e-8f;
  float nre = abr - 1.0f + eps, nim = abi;
  float qre = dre + eps,        qim = dim;
  float inv = 1.0f / (qre*qre + qim*qim);
  float bbr = dt * (nre*qre + nim*qim) * inv;
  float bbi = dt * (nim*qre - nre*qim) * inv;
  float2 a  = make_float2(abr, abi);
  float2 bb = make_float2(bbr, bbi);
  float2 cc = make_float2(C_re[idx], C_im[idx]);

  // W chain (B-operand layout, rows n2, cols s)
  {
    ushort* Wr = W2t + ((size_t)d * 128 + 2*n) * 64;
    float2 w = bb;
    for (int s = TT - 1; s >= 0; --s) {
      Wr[s]      = (ushort)f2b(w.x);
      Wr[64 + s] = (ushort)f2b(w.y);   // row 2n+1
      w = cmul(w, a);
    }
  }
  // G chain (B-operand layout, rows r, cols n2; -Im folded)
  {
    float2 g = cmul(cc, a);
    for (int r = 0; r < TT; ++r) {
      ushort* Gr = G2t + ((size_t)d * 64 + r) * 128;
      Gr[2*n]     = (ushort)f2b(g.x);
      Gr[2*n + 1] = (ushort)f2b(-g.y);
      g = cmul(g, a);
    }
  }
  // P = a^64
  {
    float2 p = a;
    #pragma unroll
    for (int q = 0; q < 6; ++q) p = cmul(p, p);
    P[idx] = p;
  }
  // K_loc[m] = Re(sum_n C*Abar^m*Bbar)  (fp32, for the exact local conv)
  float tre = cc.x*bb.x - cc.y*bb.y;
  float tim = cc.x*bb.y + cc.y*bb.x;
  for (int m = 0; m < TT; ++m) {
    float v = tre;
    #pragma unroll
    for (int off = 32; off > 0; off >>= 1) v += __shfl_down(v, off, 64);
    if (n == 0) KlocT[m * DD + d] = v;
    float t2 = tre*abr - tim*abi;
    tim = tre*abi + tim*abr;
    tre = t2;
  }
}

// ---------------------------------------------------------------------------
// K2 MFMA: Z-GEMM + in-block scan + cross-GEMM. One block (256 thr) per (b,d).
// XCD swizzle: XCD x hosts d in [x*64,x*64+64) -> W2t/G2t stay L2-hot.
//  stage: u column -> bf16 LDS tile u_lds[c][s], XOR-swizzled rows
//  B: Z[c][n2] = sum_s U[c][s]*W2[s][n2]   M=32,N=128,K=64  (16 MFMA/wave)
//  C: scan (wave 0, fp32 state): Zs[c] <- S_c (bf16)
//  D: ycross[c][r] = sum_n2 S2[c][n2]*G2[n2][r]  M=32,N=64,K=128 (8 MFMA/wave)
// LDS 12 KB. MFMA frag layouts (16x16x32): A row=l&15, k=(l>>4)*8+e;
// B col=l&15, k=(l>>4)*8+e; C/D col=l&15, row=(l>>4)*4+reg.
// ---------------------------------------------------------------------------
__global__ __launch_bounds__(256, 6) void k2_mfma(
    const float* __restrict__ u, const ushort* __restrict__ W2t,
    const ushort* __restrict__ G2t, const float2* __restrict__ P,
    float* __restrict__ ycross) {
  int bid = blockIdx.x;
  int x = bid & 7;                     // XCD
  int d = x * 64 + ((bid >> 3) & 63);  // d-contiguous per XCD
  int b = bid >> 9;
  int tid = threadIdx.x;
  int l  = tid & 63, wv = tid >> 6;
  int lr = l & 15,   lk = l >> 4;

  __shared__ __align__(16) char smem[4096 + 8192];
  char* u_lds = smem;                  // [32 c][128 B] bf16, swizzled
  char* Zs    = smem + 4096;           // [32 c][256 B] bf16, swizzled

  // --- stage u column as bf16 (8 consecutive s per thread -> 1 b128 write)
  {
    int i0 = tid * 8;
    const float* up = u + ((size_t)b * LL + i0) * DD + d;
    float uf[8];
    #pragma unroll
    for (int j = 0; j < 8; ++j) uf[j] = up[(size_t)j * DD];
    uint4 pk;
    pk.x = f2b(uf[0]) | (f2b(uf[1]) << 16);
    pk.y = f2b(uf[2]) | (f2b(uf[3]) << 16);
    pk.z = f2b(uf[4]) | (f2b(uf[5]) << 16);
    pk.w = f2b(uf[6]) | (f2b(uf[7]) << 16);
    int row = tid >> 3;                // c
    int bo  = row * 128 + (((tid & 7) * 16) ^ ((row & 7) << 4));
    *(uint4*)(u_lds + bo) = pk;
  }
  __syncthreads();

  // --- B: wave wv -> Mtile m0=(wv&1)*16, Ntiles n0=(wv>>1)*64 .. +64
  {
    int m0 = (wv & 1) * 16;
    int n0 = (wv >> 1) * 64;
    const ushort* Wd = W2t + (size_t)d * 128 * 64;
    f32x4 acc[4] = {{0,0,0,0},{0,0,0,0},{0,0,0,0},{0,0,0,0}};
    #pragma unroll
    for (int ks = 0; ks < 2; ++ks) {
      int row = m0 + lr;
      bf16x8 af = *(const bf16x8*)(u_lds + row*128 +
                     ((ks*64 + lk*16) ^ ((row & 7) << 4)));
      #pragma unroll
      for (int t = 0; t < 4; ++t) {
        bf16x8 bf = *(const bf16x8*)(Wd + (n0 + t*16 + lr)*64 + ks*32 + lk*8);
        acc[t] = __builtin_amdgcn_mfma_f32_16x16x32_bf16(af, bf, acc[t], 0,0,0);
      }
    }
    __syncthreads();                   // (defensive: u_lds fully read)
    #pragma unroll
    for (int t = 0; t < 4; ++t)
      #pragma unroll
      for (int j = 0; j < 4; ++j) {
        int c  = m0 + lk*4 + j;
        int n2 = n0 + t*16 + lr;
        *(ushort*)(Zs + c*256 + ((n2*2) ^ ((c & 7) << 4))) =
            (ushort)f2b(acc[t][j]);
      }
  }
  __syncthreads();

  // --- C: scan (wave 0): Zs[c] := S_c (bf16); S_{c+1} = a^64*S_c + Z_c (f32)
  if (wv == 0) {
    float2 p = P[(size_t)d * NN + l];
    float sx = 0.f, sy = 0.f;
    for (int c = 0; c < CC; ++c) {
      unsigned off = c*256 + ((l*4) ^ ((c & 7) << 4));
      unsigned zz = *(unsigned*)(Zs + off);
      float zx = b2f(zz & 0xffffu), zy = b2f(zz >> 16);
      *(unsigned*)(Zs + off) = f2b(sx) | (f2b(sy) << 16);
      float nsx = p.x*sx - p.y*sy + zx;
      float nsy = p.x*sy + p.y*sx + zy;
      sx = nsx; sy = nsy;
    }
  }
  __syncthreads();

  // --- D: wave wv -> Mtile m0=(wv&1)*16, r-tiles r0=(wv>>1)*32 .. +32
  {
    int m0 = (wv & 1) * 16;
    int r0 = (wv >> 1) * 32;
    const ushort* Gd = G2t + (size_t)d * 64 * 128;
    f32x4 acc2[2] = {{0,0,0,0},{0,0,0,0}};
    #pragma unroll
    for (int ks = 0; ks < 4; ++ks) {
      int row = m0 + lr;
      bf16x8 af = *(const bf16x8*)(Zs + row*256 +
                     ((ks*64 + lk*16) ^ ((row & 7) << 4)));
      #pragma unroll
      for (int t = 0; t < 2; ++t) {
        bf16x8 bf = *(const bf16x8*)(Gd + (r0 + t*16 + lr)*128 + ks*32 + lk*8);
        acc2[t] = __builtin_amdgcn_mfma_f32_16x16x32_bf16(af, bf, acc2[t], 0,0,0);
      }
    }
    float* yp = ycross + ((size_t)d * 256 + b * CC) * TT;
    #pragma unroll
    for (int t = 0; t < 2; ++t)
      #pragma unroll
      for (int j = 0; j < 4; ++j) {
        int c = m0 + lk*4 + j;
        int r = r0 + t*16 + lr;
        yp[c*64 + r] = acc2[t][j];
      }
  }
}

// ---------------------------------------------------------------------------
// K3b: local causal 64-tap conv (fp32, exact) + cross term, coalesced writes.
// ---------------------------------------------------------------------------
__global__ __launch_bounds__(256, 2) void k3b_out(
    const float* __restrict__ u, const float* __restrict__ KlocT,
    const float* __restrict__ ycross, float* __restrict__ y) {
  int bid = blockIdx.x;
  int d8 = bid & 7;
  int c  = (bid >> 3) & (CC - 1);
  int b  = bid >> 8;
  int d0 = d8 * 64;
  int tid = threadIdx.x;
  int dd = tid & 63, rq = tid >> 6;
  __shared__ float ulp[128][64];       // ulp[63+t][dd]=u[cT+t], rows<63 = 0
  __shared__ float Ktl[TT][64];
  __shared__ float ycl[64][65];
  for (int i = tid; i < 63 * 64; i += 256)
    ulp[i >> 6][i & 63] = 0.f;
  for (int i = tid; i < TT * 64; i += 256) {
    int s = i >> 6, e = i & 63;
    ulp[63 + s][e] = u[((size_t)b * LL + c * TT + s) * DD + d0 + e];
    Ktl[s][e] = KlocT[s * DD + d0 + e];
  }
  for (int i = tid; i < 64 * TT; i += 256) {
    int e = i >> 6, r = i & 63;
    ycl[e][r] = ycross[((size_t)(d0 + e) * 256 + b * CC + c) * TT + r];
  }
  __syncthreads();
  #pragma unroll 1
  for (int pass = 0; pass < 2; ++pass) {
    int rg = rq + 4 * pass;            // wave-uniform
    int r0 = rg * 8;
    float acc[8], w[8];
    #pragma unroll
    for (int j = 0; j < 8; ++j) acc[j] = ycl[dd][r0 + j];
    #pragma unroll
    for (int j = 0; j < 8; ++j) w[j] = ulp[63 + r0 + j][dd];
    for (int m0 = 0; m0 <= r0; m0 += 8) {
      #pragma unroll
      for (int mm = 0; mm < 8; ++mm) {
        float kv = Ktl[m0 + mm][dd];
        #pragma unroll
        for (int j = 0; j < 8; ++j)
          acc[j] = fmaf(kv, w[(j - mm) & 7], acc[j]);
        w[(7 - mm) & 7] = ulp[63 + r0 - 1 - (m0 + mm)][dd];
      }
    }
    #pragma unroll
    for (int j = 0; j < 8; ++j)
      y[((size_t)b * LL + c * TT + r0 + j) * DD + d0 + dd] = acc[j];
  }
}

extern "C" void kernel_launch(void* const* d_in, const int* in_sizes, int n_in,
                              void* d_out, int out_size, void* d_ws, size_t ws_size,
                              hipStream_t stream) {
  const float* u      = (const float*)d_in[0];
  const float* A_re   = (const float*)d_in[1];
  const float* A_im   = (const float*)d_in[2];
  const float* C_re   = (const float*)d_in[3];
  const float* C_im   = (const float*)d_in[4];
  const float* log_dt = (const float*)d_in[5];
  float* y  = (float*)d_out;
  float* ws = (float*)d_ws;

  // ws: ycross f32 33.6MB | W2t bf16 8.4MB | G2t bf16 8.4MB | P f32 | KlocT
  float*  ycross = ws;
  ushort* W2t    = (ushort*)(ycross + (size_t)DD * 256 * TT);
  ushort* G2t    = W2t + (size_t)DD * 128 * 64;
  float2* P      = (float2*)(G2t + (size_t)DD * 64 * 128);
  float*  KlocT  = (float*)(P + DD * NN);

  k1_setup<<<DD,                64,  0, stream>>>(A_re, A_im, C_re, C_im, log_dt,
                                                  W2t, G2t, P, KlocT);
  k2_mfma <<<BB * DD,           256, 0, stream>>>(u, W2t, G2t, P, ycross);
  k3b_out <<<BB * CC * (DD/64), 256, 0, stream>>>(u, KlocT, ycross, y);
}

// Round 7
// 86.988 us; speedup vs baseline: 2.2589x; 1.3077x over previous
//
#include <hip/hip_runtime.h>

#define BB 8
#define LL 2048
#define DD 512
#define NN 64
#define TT 64
#define CC 32   // LL/TT chunks

typedef __attribute__((ext_vector_type(8))) short bf16x8;
typedef __attribute__((ext_vector_type(4))) float f32x4;

__device__ __forceinline__ float2 cmul(float2 a, float2 b) {
  return make_float2(a.x*b.x - a.y*b.y, a.x*b.y + a.y*b.x);
}
__device__ __forceinline__ unsigned f2b(float f) {   // f32 -> bf16 (RNE)
  union { float f; unsigned u; } v; v.f = f;
  return (v.u + 0x7FFFu + ((v.u >> 16) & 1u)) >> 16;
}

// ---------------------------------------------------------------------------
// K0: transpose u[b][l][d] f32 -> ut[b][d][l] bf16. Both sides coalesced.
// Block = (b, l-tile 64, d-tile 64).
// ---------------------------------------------------------------------------
__global__ __launch_bounds__(256) void k0_tr(
    const float* __restrict__ u, ushort* __restrict__ ut) {
  int bid = blockIdx.x;
  int dt = bid & 7, lt = (bid >> 3) & 31, b = bid >> 8;
  int l0 = lt * 64, d0 = dt * 64;
  int tid = threadIdx.x;
  __shared__ ushort tl[64][65];
  int lane16 = tid & 15, rowq = tid >> 4;
  #pragma unroll
  for (int it = 0; it < 4; ++it) {
    int i = it * 16 + rowq;
    float4 v = *(const float4*)&u[((size_t)(b*LL + l0 + i))*DD + d0 + lane16*4];
    tl[i][lane16*4+0] = (ushort)f2b(v.x);
    tl[i][lane16*4+1] = (ushort)f2b(v.y);
    tl[i][lane16*4+2] = (ushort)f2b(v.z);
    tl[i][lane16*4+3] = (ushort)f2b(v.w);
  }
  __syncthreads();
  int row = tid >> 2, seg = tid & 3;
  union { ushort us[16]; uint4 v4[2]; } tmp;
  #pragma unroll
  for (int q = 0; q < 16; ++q) tmp.us[q] = tl[seg*16 + q][row];
  uint4* dst = (uint4*)&ut[((size_t)(b*DD + d0 + row))*LL + l0 + seg*16];
  dst[0] = tmp.v4[0]; dst[1] = tmp.v4[1];
}

// ---------------------------------------------------------------------------
// K1: per-d setup. Emits PRE-SWIZZLED bf16 MFMA B-operand tables so k2's
// loads are contiguous 1KB/wave:
//  W2s[d]: frag order (nh, t, ks, l, e): row n2=nh*64+t*16+(l&15),
//          k s=ks*32+(l>>4)*8+e, value: n2 even Re(W), odd Im(W),
//          W[s]=Abar^(63-s)*Bbar.
//  G2s[d]: frag order (rh, t, ks, l, e): row r=rh*32+t*16+(l&15),
//          k n2=ks*32+(l>>4)*8+e, value: n2 even Re(G), odd -Im(G),
//          G[r]=C*Abar^(r+1).
//  P[d][n]=Abar^64 (f32); KlocT[m][d] (f32 conv taps).
// Staged in LDS, copied out coalesced.
// ---------------------------------------------------------------------------
__global__ __launch_bounds__(64) void k1_setup(
    const float* __restrict__ A_re, const float* __restrict__ A_im,
    const float* __restrict__ C_re, const float* __restrict__ C_im,
    const float* __restrict__ log_dt,
    ushort* __restrict__ W2s, ushort* __restrict__ G2s,
    float2* __restrict__ P, float* __restrict__ KlocT) {
  int d = blockIdx.x, n = threadIdx.x;
  int idx = d * NN + n;
  __shared__ ushort Wl[8192], Gl[8192];
  float dt  = expf(log_dt[d]);
  float dre = dt * A_re[idx], dim = dt * A_im[idx];
  float er  = expf(dre);
  float abr = er * cosf(dim), abi = er * sinf(dim);
  const float eps = 1e-8f;
  float nre = abr - 1.0f + eps, nim = abi;
  float qre = dre + eps,        qim = dim;
  float inv = 1.0f / (qre*qre + qim*qim);
  float bbr = dt * (nre*qre + nim*qim) * inv;
  float bbi = dt * (nim*qre - nre*qim) * inv;
  float2 a  = make_float2(abr, abi);
  float2 bb = make_float2(bbr, bbi);
  float2 cc = make_float2(C_re[idx], C_im[idx]);

  // W frags
  {
    float2 w = bb;
    for (int s = TT - 1; s >= 0; --s) {
      int ks = s >> 5, lk = (s >> 3) & 3, e = s & 7;
      {
        int n2 = 2*n; int nh = n2>>6, t = (n2>>4)&3, lr = n2&15, l = lk*16+lr;
        Wl[(((nh*4+t)*2+ks)*64 + l)*8 + e] = (ushort)f2b(w.x);
      }
      {
        int n2 = 2*n+1; int nh = n2>>6, t = (n2>>4)&3, lr = n2&15, l = lk*16+lr;
        Wl[(((nh*4+t)*2+ks)*64 + l)*8 + e] = (ushort)f2b(w.y);
      }
      w = cmul(w, a);
    }
  }
  // G frags
  {
    float2 g = cmul(cc, a);
    for (int r = 0; r < TT; ++r) {
      int rh = r >> 5, t = (r >> 4) & 1, lr = r & 15;
      {
        int n2 = 2*n; int ks = n2>>5, lk = (n2>>3)&3, e = n2&7, l = lk*16+lr;
        Gl[(((rh*2+t)*4+ks)*64 + l)*8 + e] = (ushort)f2b(g.x);
      }
      {
        int n2 = 2*n+1; int ks = n2>>5, lk = (n2>>3)&3, e = n2&7, l = lk*16+lr;
        Gl[(((rh*2+t)*4+ks)*64 + l)*8 + e] = (ushort)f2b(-g.y);
      }
      g = cmul(g, a);
    }
  }
  // P = a^64
  {
    float2 p = a;
    #pragma unroll
    for (int q = 0; q < 6; ++q) p = cmul(p, p);
    P[idx] = p;
  }
  // K_loc[m] = Re(sum_n C*Abar^m*Bbar)
  {
    float tre = cc.x*bb.x - cc.y*bb.y;
    float tim = cc.x*bb.y + cc.y*bb.x;
    for (int m = 0; m < TT; ++m) {
      float v = tre;
      #pragma unroll
      for (int off = 32; off > 0; off >>= 1) v += __shfl_down(v, off, 64);
      if (n == 0) KlocT[m * DD + d] = v;
      float t2 = tre*abr - tim*abi;
      tim = tre*abi + tim*abr;
      tre = t2;
    }
  }
  __syncthreads();
  // coalesced copy-out (16KB each)
  {
    uint4* Wg = (uint4*)(W2s + (size_t)d * 8192);
    uint4* Gg = (uint4*)(G2s + (size_t)d * 8192);
    const uint4* Wls = (const uint4*)Wl;
    const uint4* Gls = (const uint4*)Gl;
    for (int i = n; i < 1024; i += 64) { Wg[i] = Wls[i]; Gg[i] = Gls[i]; }
  }
}

// ---------------------------------------------------------------------------
// K2 MFMA: Z-GEMM + Kogge-Stone scan + cross-GEMM. Block (256 thr) per (b,d).
// XCD swizzle: XCD x hosts d in [x*64,x*64+64) -> ut/W/G slice = 4MB = L2.
//  stage: 1 coalesced 16B load/thread from ut -> swizzled u_lds[c][s]
//  B: Z[c][n2] = sum_s U[c][s]*W[s][n2]  (8 MFMA/wave); acc -> f32 Sf rows
//  scan: Kogge-Stone over 32 chunks, all 256 threads, 5 steps, f32 in LDS
//  D: ycross[c][r] = sum_n2 Sexcl[c][n2]*G[n2][r]  (8 MFMA/wave)
// Sf row r holds inclusive[r-1] = S_excl[r]; row 0 = 0.
// ---------------------------------------------------------------------------
__global__ __launch_bounds__(256, 5) void k2_mfma(
    const ushort* __restrict__ ut, const ushort* __restrict__ W2s,
    const ushort* __restrict__ G2s, const float2* __restrict__ P,
    float* __restrict__ ycross) {
  int bid = blockIdx.x;
  int x = bid & 7;                     // XCD
  int d = x * 64 + ((bid >> 3) & 63);  // d-contiguous per XCD
  int b = bid >> 9;
  int tid = threadIdx.x;
  int l = tid & 63, wv = tid >> 6;
  int lr = l & 15, lk = l >> 4;

  __shared__ __align__(16) char u_lds[4096];       // [32 c][128B] swizzled
  __shared__ float Sf[33 * 130];                   // [r][re:0-63 | im:64-127]
  __shared__ __align__(16) char Zs[33 * 256];      // bf16 S_excl, swizzled

  // --- stage u (fully coalesced: 256 x 16B = 4KB contiguous)
  {
    uint4 v = *(const uint4*)&ut[((size_t)(b * DD + d)) * LL + tid * 8];
    int row = tid >> 3;
    int bo = row * 128 + (((tid & 7) * 16) ^ ((row & 7) << 4));
    *(uint4*)(u_lds + bo) = v;
  }
  for (int i = tid; i < 130; i += 256) Sf[i] = 0.f;   // row 0 = zeros
  __syncthreads();

  // --- B: wave wv -> m-half (wv&1), n-half (wv>>1)
  {
    int m0 = (wv & 1) * 16;
    int nh = wv >> 1;
    const ushort* Wd = W2s + (size_t)d * 8192 + (size_t)nh * 4096;
    f32x4 acc[4] = {{0,0,0,0},{0,0,0,0},{0,0,0,0},{0,0,0,0}};
    #pragma unroll
    for (int ks = 0; ks < 2; ++ks) {
      int row = m0 + lr;
      bf16x8 af = *(const bf16x8*)(u_lds + row*128 +
                     ((ks*64 + lk*16) ^ ((row & 7) << 4)));
      #pragma unroll
      for (int t = 0; t < 4; ++t) {
        bf16x8 bfr = *(const bf16x8*)(Wd + ((t*2 + ks)*64 + l)*8);  // 1KB/wave
        acc[t] = __builtin_amdgcn_mfma_f32_16x16x32_bf16(af, bfr, acc[t], 0,0,0);
      }
    }
    #pragma unroll
    for (int t = 0; t < 4; ++t)
      #pragma unroll
      for (int j = 0; j < 4; ++j) {
        int c  = m0 + lk*4 + j;
        int n2 = nh*64 + t*16 + lr;
        int col = (n2 >> 1) + (n2 & 1) * 64;       // de-interleaved re/im
        Sf[(c + 1) * 130 + col] = acc[t][j];
      }
  }
  __syncthreads();

  // --- Kogge-Stone scan over rows 1..32: S[r] += p^(2^k) * S[r-2^k]
  {
    int n = tid & 63;
    int rb = 1 + (tid >> 6);                       // rows rb, rb+4, .., rb+28
    float2 p = P[(size_t)d * NN + n];              // a^64
    float vre[8], vim[8];
    #pragma unroll
    for (int q = 0; q < 8; ++q) {
      int r = rb + 4*q;
      vre[q] = Sf[r*130 + n];
      vim[q] = Sf[r*130 + 64 + n];
    }
    #pragma unroll
    for (int k = 0; k < 5; ++k) {
      int s = 1 << k;
      float pre[8], pim[8];
      #pragma unroll
      for (int q = 0; q < 8; ++q) {
        int pr = rb + 4*q - s; if (pr < 0) pr = 0; // row 0 = zeros
        pre[q] = Sf[pr*130 + n];
        pim[q] = Sf[pr*130 + 64 + n];
      }
      __syncthreads();                             // reads done
      #pragma unroll
      for (int q = 0; q < 8; ++q) {
        vre[q] = fmaf(p.x, pre[q], fmaf(-p.y, pim[q], vre[q]));
        vim[q] = fmaf(p.x, pim[q], fmaf( p.y, pre[q], vim[q]));
        Sf[(rb + 4*q)*130 + n]      = vre[q];
        Sf[(rb + 4*q)*130 + 64 + n] = vim[q];
      }
      float npx = p.x*p.x - p.y*p.y;
      p.y = 2.f * p.x * p.y; p.x = npx;            // p <- p^2
      __syncthreads();                             // writes visible
    }
    // convert own cells to bf16 Zs (interleaved re/im, XOR-swizzled)
    #pragma unroll
    for (int q = 0; q < 8; ++q) {
      int r = rb + 4*q;
      unsigned pk = f2b(vre[q]) | (f2b(vim[q]) << 16);
      *(unsigned*)(Zs + r*256 + ((4*n) ^ ((r & 7) << 4))) = pk;
    }
    if (tid < 64) *(unsigned*)(Zs + 4*tid) = 0u;   // row 0 = zeros
  }
  __syncthreads();

  // --- D: wave wv -> m-half (wv&1), r-half (wv>>1); A row c reads Zs[c]
  {
    int m0 = (wv & 1) * 16;
    int rh = wv >> 1;
    const ushort* Gd = G2s + (size_t)d * 8192 + (size_t)rh * 4096;
    f32x4 acc2[2] = {{0,0,0,0},{0,0,0,0}};
    #pragma unroll
    for (int ks = 0; ks < 4; ++ks) {
      int row = m0 + lr;
      bf16x8 af = *(const bf16x8*)(Zs + row*256 +
                     ((ks*64 + lk*16) ^ ((row & 7) << 4)));
      #pragma unroll
      for (int t = 0; t < 2; ++t) {
        bf16x8 bfr = *(const bf16x8*)(Gd + ((t*4 + ks)*64 + l)*8);  // 1KB/wave
        acc2[t] = __builtin_amdgcn_mfma_f32_16x16x32_bf16(af, bfr, acc2[t], 0,0,0);
      }
    }
    float* yp = ycross + ((size_t)d * 256 + b * CC) * TT;
    #pragma unroll
    for (int t = 0; t < 2; ++t)
      #pragma unroll
      for (int j = 0; j < 4; ++j) {
        int c = m0 + lk*4 + j;
        int r = rh*32 + t*16 + lr;
        yp[c*64 + r] = acc2[t][j];
      }
  }
}

// ---------------------------------------------------------------------------
// K3b: local causal 64-tap conv (fp32, exact) + cross term, coalesced writes.
// ---------------------------------------------------------------------------
__global__ __launch_bounds__(256, 2) void k3b_out(
    const float* __restrict__ u, const float* __restrict__ KlocT,
    const float* __restrict__ ycross, float* __restrict__ y) {
  int bid = blockIdx.x;
  int d8 = bid & 7;
  int c  = (bid >> 3) & (CC - 1);
  int b  = bid >> 8;
  int d0 = d8 * 64;
  int tid = threadIdx.x;
  int dd = tid & 63, rq = tid >> 6;
  __shared__ float ulp[128][64];       // ulp[63+t][dd]=u[cT+t], rows<63 = 0
  __shared__ float Ktl[TT][64];
  __shared__ float ycl[64][65];
  for (int i = tid; i < 63 * 64; i += 256)
    ulp[i >> 6][i & 63] = 0.f;
  for (int i = tid; i < TT * 64; i += 256) {
    int s = i >> 6, e = i & 63;
    ulp[63 + s][e] = u[((size_t)b * LL + c * TT + s) * DD + d0 + e];
    Ktl[s][e] = KlocT[s * DD + d0 + e];
  }
  for (int i = tid; i < 64 * TT; i += 256) {
    int e = i >> 6, r = i & 63;
    ycl[e][r] = ycross[((size_t)(d0 + e) * 256 + b * CC + c) * TT + r];
  }
  __syncthreads();
  #pragma unroll 1
  for (int pass = 0; pass < 2; ++pass) {
    int rg = rq + 4 * pass;            // wave-uniform
    int r0 = rg * 8;
    float acc[8], w[8];
    #pragma unroll
    for (int j = 0; j < 8; ++j) acc[j] = ycl[dd][r0 + j];
    #pragma unroll
    for (int j = 0; j < 8; ++j) w[j] = ulp[63 + r0 + j][dd];
    for (int m0 = 0; m0 <= r0; m0 += 8) {
      #pragma unroll
      for (int mm = 0; mm < 8; ++mm) {
        float kv = Ktl[m0 + mm][dd];
        #pragma unroll
        for (int j = 0; j < 8; ++j)
          acc[j] = fmaf(kv, w[(j - mm) & 7], acc[j]);
        w[(7 - mm) & 7] = ulp[63 + r0 - 1 - (m0 + mm)][dd];
      }
    }
    #pragma unroll
    for (int j = 0; j < 8; ++j)
      y[((size_t)b * LL + c * TT + r0 + j) * DD + d0 + dd] = acc[j];
  }
}

extern "C" void kernel_launch(void* const* d_in, const int* in_sizes, int n_in,
                              void* d_out, int out_size, void* d_ws, size_t ws_size,
                              hipStream_t stream) {
  const float* u      = (const float*)d_in[0];
  const float* A_re   = (const float*)d_in[1];
  const float* A_im   = (const float*)d_in[2];
  const float* C_re   = (const float*)d_in[3];
  const float* C_im   = (const float*)d_in[4];
  const float* log_dt = (const float*)d_in[5];
  float* y  = (float*)d_out;
  float* ws = (float*)d_ws;

  // ws: ycross f32 33.5MB | W2s 8.4MB | G2s 8.4MB | P | KlocT | ut bf16 16.8MB
  float*  ycross = ws;
  ushort* W2s    = (ushort*)(ycross + (size_t)DD * 256 * TT);
  ushort* G2s    = W2s + (size_t)DD * 8192;
  float2* P      = (float2*)(G2s + (size_t)DD * 8192);
  float*  KlocT  = (float*)(P + DD * NN);
  ushort* ut     = (ushort*)(KlocT + DD * TT);

  k0_tr   <<<BB * 32 * 8,       256, 0, stream>>>(u, ut);
  k1_setup<<<DD,                64,  0, stream>>>(A_re, A_im, C_re, C_im, log_dt,
                                                  W2s, G2s, P, KlocT);
  k2_mfma <<<BB * DD,           256, 0, stream>>>(ut, W2s, G2s, P, ycross);
  k3b_out <<<BB * CC * (DD/64), 256, 0, stream>>>(u, KlocT, ycross, y);
}